// Round 1
// baseline (707.774 us; speedup 1.0000x reference)
//
#include <hip/hip_runtime.h>
#include <cstdint>
#include <cstddef>

#define L_SEQ   1024
#define DMODEL  2048
#define DINNER  4096
#define DXB     1024
#define DSTATE  16
#define DTRANK  128
#define INTER   8192
#define ZROW    10368   // 2*DINNER + 2*DXB + DTRANK
#define NCHUNK  64
#define CLEN    16      // L_SEQ / NCHUNK

typedef __attribute__((ext_vector_type(8))) short  short8;
typedef __attribute__((ext_vector_type(4))) float  floatx4;
typedef unsigned short ushort_t;

__device__ __forceinline__ unsigned short f2bf(float f) {
  unsigned u = __float_as_uint(f);
  u += 0x7FFFu + ((u >> 16) & 1u);     // RNE
  return (unsigned short)(u >> 16);
}
__device__ __forceinline__ float bf2f(unsigned short h) {
  return __uint_as_float(((unsigned)h) << 16);
}

__device__ __forceinline__ void gl_lds16(const void* g, void* l) {
  __builtin_amdgcn_global_load_lds(
      (const __attribute__((address_space(1))) unsigned int*)g,
      (__attribute__((address_space(3))) unsigned int*)l,
      16, 0, 0);
}

// ---------------------------------------------------------------------------
// fp32 -> bf16 convert, 8 elems/thread
// ---------------------------------------------------------------------------
__global__ void __launch_bounds__(256) cvt_kernel(
    const float* __restrict__ src, ushort_t* __restrict__ dst, int n8)
{
  int idx = blockIdx.x * 256 + threadIdx.x;
  if (idx < n8) {
    const float4* s = (const float4*)src + (size_t)idx * 2;
    float4 v0 = s[0], v1 = s[1];
    union { ushort_t u[8]; uint4 v; } o;
    o.u[0] = f2bf(v0.x); o.u[1] = f2bf(v0.y); o.u[2] = f2bf(v0.z); o.u[3] = f2bf(v0.w);
    o.u[4] = f2bf(v1.x); o.u[5] = f2bf(v1.y); o.u[6] = f2bf(v1.z); o.u[7] = f2bf(v1.w);
    ((uint4*)dst)[idx] = o.v;
  }
}

// ---------------------------------------------------------------------------
// GEMM, ring-4 counted-vmcnt pipeline. C[m,n] = sum_k A[m,k]*W[n,k].
// bf16 in, fp32 accum. BM=BN=128, BK=32, 256 threads (4 waves, 2x2).
//  - LDS ring of 4 tile slots per operand (64 KB total): stage tile t+3
//    while computing tile t; loads get 3 iterations to land.
//  - raw s_barrier + counted s_waitcnt vmcnt(8/4/0): never drains the
//    global_load_lds queue in steady state (the m97-structure ~60% stall).
//  - XOR swizzle (chunk ^= row&3) applied via pre-swizzled GLOBAL source
//    (LDS dest must stay linear for global_load_lds) + swizzled ds_read:
//    8-way -> 4-way bank conflict.
//  - XCD-aware bijective block swizzle for L2 locality.
// EPI: 0 none, 1 softplus(acc+aux[col]). WF32: write fp32 C.
// Cb!=null: also/only write bf16 (cols >= col_lo). Split-K via blockIdx.z.
// Requires K % 32 == 0 and K >= 128 (T >= 4); all call sites satisfy this.
// ---------------------------------------------------------------------------
template <int EPI, bool WF32>
__global__ void __launch_bounds__(256, 2) gemm_ring(
    const ushort_t* __restrict__ A, int lda,
    const ushort_t* __restrict__ W, int ldw,
    float* __restrict__ C, int ldc, int K,
    const float* __restrict__ aux,
    ushort_t* __restrict__ Cb, int col_lo, int ldcb)
{
  constexpr int ASZ = 128 * 32;                 // 4096 elems = 8 KB / tile / operand
  __shared__ alignas(16) ushort_t As[4 * ASZ];  // 32 KB ring
  __shared__ alignas(16) ushort_t Bs[4 * ASZ];  // 32 KB ring

  // XCD-aware bijective swizzle (T1, m204 form) over flattened (z,y,x)
  const int gx = gridDim.x, gy = gridDim.y;
  const int nwg = gx * gy * (int)gridDim.z;
  const int id  = ((int)blockIdx.z * gy + (int)blockIdx.y) * gx + (int)blockIdx.x;
  const int q = nwg >> 3, r = nwg & 7, xc = id & 7, dd = id >> 3;
  const int wg = (xc < r ? xc * (q + 1) : r * (q + 1) + (xc - r) * q) + dd;
  const int bx  = wg % gx;
  const int byz = wg / gx;
  const int by  = byz % gy;
  const int kz  = byz / gy;

  A += (size_t)kz * K;
  W += (size_t)kz * K;
  float* Cz = nullptr;
  if constexpr (WF32) Cz = C + (size_t)kz * gy * 128 * ldc;

  const int m0 = by * 128, n0 = bx * 128;
  const int t = threadIdx.x;
  const int lane = t & 63, wave = t >> 6;
  const int wm = wave & 1, wn = wave >> 1;
  const int lrow = lane & 15, quad = lane >> 4;
  const int chunk = (quad ^ (lrow & 3)) << 3;   // swizzled 8-elem chunk for reads

  const int srow = wave * 16 + (lane >> 2);
  const int skof = (((lane & 3) ^ ((lane >> 2) & 3)) << 3);  // pre-swizzled source col

  const ushort_t* gA0 = A + (size_t)(m0 +  0 + srow) * lda + skof;
  const ushort_t* gA1 = A + (size_t)(m0 + 64 + srow) * lda + skof;
  const ushort_t* gW0 = W + (size_t)(n0 +  0 + srow) * ldw + skof;
  const ushort_t* gW1 = W + (size_t)(n0 + 64 + srow) * ldw + skof;
  ushort_t* lA0 = As + wave * 512;
  ushort_t* lA1 = As + 2048 + wave * 512;
  ushort_t* lB0 = Bs + wave * 512;
  ushort_t* lB1 = Bs + 2048 + wave * 512;

  floatx4 zero = {0.f, 0.f, 0.f, 0.f};
  floatx4 acc[4][4];
#pragma unroll
  for (int a = 0; a < 4; ++a)
#pragma unroll
    for (int b = 0; b < 4; ++b) acc[a][b] = zero;

  const int T = K >> 5;

  // prologue: stage tiles 0,1,2 into ring slots 0,1,2 (4 loads/wave/tile)
#pragma unroll
  for (int p = 0; p < 3; ++p) {
    const int ko = p * 32, s = p * ASZ;
    gl_lds16(gA0 + ko, lA0 + s);
    gl_lds16(gA1 + ko, lA1 + s);
    gl_lds16(gW0 + ko, lB0 + s);
    gl_lds16(gW1 + ko, lB1 + s);
  }

  for (int tt = 0; tt < T; ++tt) {
    // retire tile tt's 4 loads; keep up to 2 newer tiles (8 loads) in flight
    if (tt + 2 < T)      asm volatile("s_waitcnt vmcnt(8)" ::: "memory");
    else if (tt + 1 < T) asm volatile("s_waitcnt vmcnt(4)" ::: "memory");
    else                 asm volatile("s_waitcnt vmcnt(0)" ::: "memory");
    __builtin_amdgcn_s_barrier();
    __builtin_amdgcn_sched_barrier(0);

    if (tt + 3 < T) {
      const int ko = (tt + 3) * 32;
      const int s  = ((tt + 3) & 3) * ASZ;     // slot last read in iter tt-1: safe
      gl_lds16(gA0 + ko, lA0 + s);
      gl_lds16(gA1 + ko, lA1 + s);
      gl_lds16(gW0 + ko, lB0 + s);
      gl_lds16(gW1 + ko, lB1 + s);
    }

    const int cs = (tt & 3) * ASZ;
    short8 af[4], bf_[4];
#pragma unroll
    for (int mi = 0; mi < 4; ++mi)
      af[mi] = *(const short8*)&As[cs + (wm * 64 + mi * 16 + lrow) * 32 + chunk];
#pragma unroll
    for (int ni = 0; ni < 4; ++ni)
      bf_[ni] = *(const short8*)&Bs[cs + (wn * 64 + ni * 16 + lrow) * 32 + chunk];
#pragma unroll
    for (int mi = 0; mi < 4; ++mi)
#pragma unroll
      for (int ni = 0; ni < 4; ++ni)
        acc[mi][ni] = __builtin_amdgcn_mfma_f32_16x16x32_bf16(af[mi], bf_[ni], acc[mi][ni], 0, 0, 0);
  }

#pragma unroll
  for (int mi = 0; mi < 4; ++mi)
#pragma unroll
    for (int ni = 0; ni < 4; ++ni)
#pragma unroll
      for (int reg = 0; reg < 4; ++reg) {
        int row = m0 + wm * 64 + mi * 16 + quad * 4 + reg;
        int col = n0 + wn * 64 + ni * 16 + lrow;
        float v = acc[mi][ni][reg];
        if (EPI == 1) {
          v += aux[col];
          v = (v > 20.f) ? v : log1pf(__expf(v));
        }
        if constexpr (WF32)
          Cz[(size_t)row * ldc + col] = v;
        if (Cb != nullptr && col >= col_lo)
          Cb[(size_t)row * ldcb + (col - col_lo)] = f2bf(v);
      }
}

// ---------------------------------------------------------------------------
// split-K reduce: out = aux + sum_{s<S} part[s]   (fp32, float4)
// ---------------------------------------------------------------------------
template <int S>
__global__ void __launch_bounds__(256) reduce_add_kernel(
    const float* __restrict__ part, int stride4,
    const float* __restrict__ aux, float* __restrict__ out, int n4)
{
  int idx = blockIdx.x * 256 + threadIdx.x;
  if (idx < n4) {
    float4 v = ((const float4*)aux)[idx];
#pragma unroll
    for (int s = 0; s < S; ++s) {
      float4 p = ((const float4*)part)[(size_t)s * stride4 + idx];
      v.x += p.x; v.y += p.y; v.z += p.z; v.w += p.w;
    }
    ((float4*)out)[idx] = v;
  }
}

// ---------------------------------------------------------------------------
// Fused: h2 = hidden + sum_s part[s]; hn_bf = rmsnorm(h2)*w  (one block/row)
// ---------------------------------------------------------------------------
__global__ void __launch_bounds__(256) reduce_rms_kernel(
    const float* __restrict__ part, int stride,   // stride in floats
    const float* __restrict__ hidden,
    const float* __restrict__ w,
    float* __restrict__ h2, ushort_t* __restrict__ hn)
{
  const int row = blockIdx.x;
  const int c0 = threadIdx.x * 8;            // 2048/256 = 8 floats/thread
  float4 v0 = *(const float4*)(hidden + (size_t)row * DMODEL + c0);
  float4 v1 = *(const float4*)(hidden + (size_t)row * DMODEL + c0 + 4);
#pragma unroll
  for (int s = 0; s < 4; ++s) {
    const float* p = part + (size_t)s * stride + (size_t)row * DMODEL + c0;
    float4 p0 = *(const float4*)p;
    float4 p1 = *(const float4*)(p + 4);
    v0.x += p0.x; v0.y += p0.y; v0.z += p0.z; v0.w += p0.w;
    v1.x += p1.x; v1.y += p1.y; v1.z += p1.z; v1.w += p1.w;
  }
  *(float4*)(h2 + (size_t)row * DMODEL + c0)     = v0;
  *(float4*)(h2 + (size_t)row * DMODEL + c0 + 4) = v1;
  float ss = v0.x*v0.x + v0.y*v0.y + v0.z*v0.z + v0.w*v0.w
           + v1.x*v1.x + v1.y*v1.y + v1.z*v1.z + v1.w*v1.w;
#pragma unroll
  for (int off = 32; off > 0; off >>= 1) ss += __shfl_down(ss, off);
  __shared__ float red[5];
  const int lane = threadIdx.x & 63, wv = threadIdx.x >> 6;
  if (lane == 0) red[wv] = ss;
  __syncthreads();
  if (threadIdx.x == 0)
    red[4] = rsqrtf((red[0] + red[1] + red[2] + red[3]) / (float)DMODEL + 1e-5f);
  __syncthreads();
  const float scale = red[4];
  float4 w0 = *(const float4*)(w + c0);
  float4 w1 = *(const float4*)(w + c0 + 4);
  union { ushort_t u[8]; uint4 q; } o;
  o.u[0] = f2bf(v0.x * scale * w0.x); o.u[1] = f2bf(v0.y * scale * w0.y);
  o.u[2] = f2bf(v0.z * scale * w0.z); o.u[3] = f2bf(v0.w * scale * w0.w);
  o.u[4] = f2bf(v1.x * scale * w1.x); o.u[5] = f2bf(v1.y * scale * w1.y);
  o.u[6] = f2bf(v1.z * scale * w1.z); o.u[7] = f2bf(v1.w * scale * w1.w);
  *(uint4*)(hn + (size_t)row * DMODEL + c0) = o.q;
}

// ---------------------------------------------------------------------------
// RMSNorm (fp32 in, bf16 out)
// ---------------------------------------------------------------------------
__global__ void __launch_bounds__(256) rmsnorm_kernel(
    const float* __restrict__ x, const float* __restrict__ w,
    ushort_t* __restrict__ out)
{
  const int row = blockIdx.x;
  const float* xr = x + (size_t)row * DMODEL;
  float ss = 0.f;
#pragma unroll
  for (int c = threadIdx.x * 4; c < DMODEL; c += 256 * 4) {
    float4 v = *(const float4*)(xr + c);
    ss += v.x * v.x + v.y * v.y + v.z * v.z + v.w * v.w;
  }
#pragma unroll
  for (int off = 32; off > 0; off >>= 1) ss += __shfl_down(ss, off);
  __shared__ float red[5];
  const int lane = threadIdx.x & 63, wv = threadIdx.x >> 6;
  if (lane == 0) red[wv] = ss;
  __syncthreads();
  if (threadIdx.x == 0)
    red[4] = rsqrtf((red[0] + red[1] + red[2] + red[3]) / (float)DMODEL + 1e-5f);
  __syncthreads();
  const float scale = red[4];
  ushort_t* orow = out + (size_t)row * DMODEL;
#pragma unroll
  for (int c = threadIdx.x * 4; c < DMODEL; c += 256 * 4) {
    float4 v  = *(const float4*)(xr + c);
    float4 w4 = *(const float4*)(w + c);
    ushort4 o;
    o.x = f2bf(v.x * scale * w4.x); o.y = f2bf(v.y * scale * w4.y);
    o.z = f2bf(v.z * scale * w4.z); o.w = f2bf(v.w * scale * w4.w);
    *(ushort4*)(orow + c) = o;
  }
}

// ---------------------------------------------------------------------------
// Chunk-parallel selective scan, channel-per-lane (16 states in registers,
// no cross-lane ops). NCHUNK=64 chunks of CLEN=16.
// Thread gt: channel i = gt & 4095, chunk c = gt >> 12.
// ---------------------------------------------------------------------------
__global__ void __launch_bounds__(256) scan_phase1(
    const float* __restrict__ zx, const float* __restrict__ dt,
    const float* __restrict__ A_log,
    float* __restrict__ hend, float* __restrict__ sdtb)
{
  const int gt = blockIdx.x * 256 + threadIdx.x;   // 0..262143
  const int i  = gt & 4095;
  const int c  = gt >> 12;
  const int l0 = c * CLEN;

  float a[16];
  *(float4*)&a[0]  = *(const float4*)(A_log + i * 16 + 0);
  *(float4*)&a[4]  = *(const float4*)(A_log + i * 16 + 4);
  *(float4*)&a[8]  = *(const float4*)(A_log + i * 16 + 8);
  *(float4*)&a[12] = *(const float4*)(A_log + i * 16 + 12);
#pragma unroll
  for (int n = 0; n < 16; ++n) a[n] = -__expf(a[n]);

  float h[16];
#pragma unroll
  for (int n = 0; n < 16; ++n) h[n] = 0.f;
  float sdt = 0.f;

  const int xci = DINNER + ((i >> 6) << 4) + (i & 15);
  const int bci = DINNER + DXB + ((i >> 6) << 4);
  const float* zr = zx + (size_t)l0 * ZROW;
  const float* dr = dt + (size_t)l0 * DINNER + i;

#pragma unroll 4
  for (int l = 0; l < CLEN; ++l) {
    const float* row = zr + l * ZROW;
    const float d = dr[l * DINNER];
    const float x = row[xci];
    float B[16];
    *(float4*)&B[0]  = *(const float4*)(row + bci);
    *(float4*)&B[4]  = *(const float4*)(row + bci + 4);
    *(float4*)&B[8]  = *(const float4*)(row + bci + 8);
    *(float4*)&B[12] = *(const float4*)(row + bci + 12);
    sdt += d;
    const float dtx = d * x;
#pragma unroll
    for (int n = 0; n < 16; ++n)
      h[n] = __expf(d * a[n]) * h[n] + dtx * B[n];
  }

  float* he = hend + ((size_t)c * 65536 + i * 16);
  *(float4*)(he + 0)  = *(float4*)&h[0];
  *(float4*)(he + 4)  = *(float4*)&h[4];
  *(float4*)(he + 8)  = *(float4*)&h[8];
  *(float4*)(he + 12) = *(float4*)&h[12];
  sdtb[c * 4096 + i] = sdt;
}

__global__ void __launch_bounds__(256) scan_phase2(
    const float* __restrict__ hend, const float* __restrict__ sdtb,
    const float* __restrict__ A_log,
    float* __restrict__ hstart)
{
  const int cs = blockIdx.x * 256 + threadIdx.x;   // 0..65535 = i*16+n
  const float a = -__expf(A_log[cs]);
  const int i  = cs >> 4;
  float H = 0.f;
#pragma unroll 8
  for (int c = 0; c < NCHUNK; ++c) {
    hstart[c * 65536 + cs] = H;
    H = __expf(a * sdtb[c * 4096 + i]) * H + hend[c * 65536 + cs];
  }
}

__global__ void __launch_bounds__(256) scan_phase3(
    const float* __restrict__ zx, const float* __restrict__ dt,
    const float* __restrict__ A_log, const float* __restrict__ D_skip,
    const float* __restrict__ hstart,
    ushort_t* __restrict__ y)
{
  const int gt = blockIdx.x * 256 + threadIdx.x;   // 0..262143
  const int i  = gt & 4095;
  const int c  = gt >> 12;
  const int l0 = c * CLEN;

  float a[16];
  *(float4*)&a[0]  = *(const float4*)(A_log + i * 16 + 0);
  *(float4*)&a[4]  = *(const float4*)(A_log + i * 16 + 4);
  *(float4*)&a[8]  = *(const float4*)(A_log + i * 16 + 8);
  *(float4*)&a[12] = *(const float4*)(A_log + i * 16 + 12);
#pragma unroll
  for (int n = 0; n < 16; ++n) a[n] = -__expf(a[n]);
  const float dsk = D_skip[i];

  float h[16];
  const float* hs = hstart + ((size_t)c * 65536 + i * 16);
  *(float4*)&h[0]  = *(const float4*)(hs + 0);
  *(float4*)&h[4]  = *(const float4*)(hs + 4);
  *(float4*)&h[8]  = *(const float4*)(hs + 8);
  *(float4*)&h[12] = *(const float4*)(hs + 12);

  const int xci = DINNER + ((i >> 6) << 4) + (i & 15);
  const int bci = DINNER + DXB + ((i >> 6) << 4);
  const int cci = DINNER + 2 * DXB + (i & ~15);
  const float* zr = zx + (size_t)l0 * ZROW;
  const float* dr = dt + (size_t)l0 * DINNER + i;
  ushort_t*    py = y + (size_t)l0 * DINNER + i;

#pragma unroll 2
  for (int l = 0; l < CLEN; ++l) {
    const float* row = zr + l * ZROW;
    const float d = dr[l * DINNER];
    const float x = row[xci];
    const float z = row[i];
    float B[16], C[16];
    *(float4*)&B[0]  = *(const float4*)(row + bci);
    *(float4*)&B[4]  = *(const float4*)(row + bci + 4);
    *(float4*)&B[8]  = *(const float4*)(row + bci + 8);
    *(float4*)&B[12] = *(const float4*)(row + bci + 12);
    *(float4*)&C[0]  = *(const float4*)(row + cci);
    *(float4*)&C[4]  = *(const float4*)(row + cci + 4);
    *(float4*)&C[8]  = *(const float4*)(row + cci + 8);
    *(float4*)&C[12] = *(const float4*)(row + cci + 12);
    const float dtx = d * x;
    float p0 = 0.f, p1 = 0.f, p2 = 0.f, p3 = 0.f;
#pragma unroll
    for (int n = 0; n < 4; ++n) {
      h[n]      = __expf(d * a[n])      * h[n]      + dtx * B[n];
      h[n + 4]  = __expf(d * a[n + 4])  * h[n + 4]  + dtx * B[n + 4];
      h[n + 8]  = __expf(d * a[n + 8])  * h[n + 8]  + dtx * B[n + 8];
      h[n + 12] = __expf(d * a[n + 12]) * h[n + 12] + dtx * B[n + 12];
      p0 += C[n] * h[n];
      p1 += C[n + 4] * h[n + 4];
      p2 += C[n + 8] * h[n + 8];
      p3 += C[n + 12] * h[n + 12];
    }
    const float p = (p0 + p1) + (p2 + p3);
    const float sz = z / (1.f + __expf(-z));
    py[l * DINNER] = f2bf((p + dsk * x) * sz);
  }
}

// ---------------------------------------------------------------------------
// hm = silu(gate) * up, gate/up interleaved in one [L][2*INTER] bf16 buffer
// (gate cols [0,INTER), up cols [INTER,2*INTER)), 8 elems/thread
// ---------------------------------------------------------------------------
__global__ void __launch_bounds__(256) silu_mul2_kernel(
    const ushort_t* __restrict__ gu, ushort_t* __restrict__ out, int n8)
{
  const int idx = blockIdx.x * 256 + threadIdx.x;
  if (idx < n8) {
    const int row = idx >> 10;            // INTER/8 = 1024 chunks per row
    const int j   = (idx & 1023) << 3;
    const ushort_t* gp = gu + (size_t)row * (2 * INTER) + j;
    union { uint4 v; ushort_t u[8]; } gv, uv, ov;
    gv.v = *(const uint4*)gp;
    uv.v = *(const uint4*)(gp + INTER);
#pragma unroll
    for (int jj = 0; jj < 8; ++jj) {
      float gf = bf2f(gv.u[jj]), uf = bf2f(uv.u[jj]);
      ov.u[jj] = f2bf(gf / (1.f + __expf(-gf)) * uf);
    }
    *(uint4*)(out + (size_t)row * INTER + j) = ov.v;
  }
}

// ---------------------------------------------------------------------------
extern "C" void kernel_launch(void* const* d_in, const int* in_sizes, int n_in,
                              void* d_out, int out_size, void* d_ws, size_t ws_size,
                              hipStream_t stream)
{
  const float* hidden    = (const float*)d_in[0];
  const float* rms1_w    = (const float*)d_in[1];
  const float* in_proj_w = (const float*)d_in[2];
  const float* dt_proj_w = (const float*)d_in[3];
  const float* dt_proj_b = (const float*)d_in[4];
  const float* A_log     = (const float*)d_in[5];
  const float* D_skip    = (const float*)d_in[6];
  const float* out_proj_w= (const float*)d_in[7];
  const float* rms2_w    = (const float*)d_in[8];
  const float* gate_w    = (const float*)d_in[9];
  const float* up_w      = (const float*)d_in[10];
  const float* down_w    = (const float*)d_in[11];
  float* out = (float*)d_out;

  char* ws = (char*)d_ws;
  // ---- arena (max end 169,607,168; ws proven >= 177,471,488) ----
  ushort_t* h_norm_bf = (ushort_t*)(ws + 0);            // 4 MB
  float*    h2        = (float*)   (ws + 4194304);      // 8 MB
  ushort_t* hn_bf     = (ushort_t*)(ws + 12582912);     // 4 MB
  // SLAB1 [16,777,216 .. 67,108,864): zxbcdt -> part1 -> gu_bf
  float*    zxbcdt    = (float*)   (ws + 16777216);     // 42,467,328
  float*    part1     = (float*)   (ws + 16777216);     // 33,554,432 (after scan)
  ushort_t* gu_bf     = (ushort_t*)(ws + 16777216);     // 32 MB (after reduce_rms)
  ushort_t* hm_bf     = (ushort_t*)(ws + 50331648);     // 16 MB
  // [67,108,864 .. 134,217,728): dtbuf+hend+hstart+sdt -> guw_bf / part2
  float*    dtbuf     = (float*)   (ws + 67108864);     // 16 MB
  ushort_t* guw_bf    = (ushort_t*)(ws + 67108864);     // 64 MB (MLP stage, after scan)
  float*    part2     = (float*)   (ws + 67108864);     // 33,554,432 (after gate/up gemm)
  float*    hend_s    = (float*)   (ws + 83886080);     // 16 MB
  float*    hstart_s  = (float*)   (ws + 100663296);    // 16 MB
  float*    sdtb_s    = (float*)   (ws + 117440512);    //  1 MB
  ushort_t* ybuf_bf   = (ushort_t*)(ws + 118489088);    //  8 MB
  ushort_t* dtA_bf    = (ushort_t*)(ws + 126877696);    //  262,144
  ushort_t* wbuf      = (ushort_t*)(ws + 127139840);    // 42,467,328

  // 1) rmsnorm1 -> bf16
  rmsnorm_kernel<<<L_SEQ, 256, 0, stream>>>(hidden, rms1_w, h_norm_bf);
  // 2) in_proj -> zxbcdt fp32 (+ bf16 dt slice)
  cvt_kernel<<<(ZROW * DMODEL / 8 + 255) / 256, 256, 0, stream>>>(in_proj_w, wbuf, ZROW * DMODEL / 8);
  gemm_ring<0, true><<<dim3(ZROW / 128, L_SEQ / 128, 1), 256, 0, stream>>>(
      h_norm_bf, DMODEL, wbuf, DMODEL, zxbcdt, ZROW, DMODEL, nullptr,
      dtA_bf, 2 * DINNER + 2 * DXB, DTRANK);
  // 3) dt = softplus(dt_in @ dt_proj_w.T + b)   (K=128 -> T=4, ring handles)
  cvt_kernel<<<(DINNER * DTRANK / 8 + 255) / 256, 256, 0, stream>>>(dt_proj_w, wbuf, DINNER * DTRANK / 8);
  gemm_ring<1, true><<<dim3(DINNER / 128, L_SEQ / 128, 1), 256, 0, stream>>>(
      dtA_bf, DTRANK, wbuf, DTRANK, dtbuf, DINNER, DTRANK, dt_proj_b,
      nullptr, 0, 0);
  // 4) chunk-parallel scan -> ybuf bf16
  scan_phase1<<<1024, 256, 0, stream>>>(zxbcdt, dtbuf, A_log, hend_s, sdtb_s);
  scan_phase2<<<256, 256, 0, stream>>>(hend_s, sdtb_s, A_log, hstart_s);
  scan_phase3<<<1024, 256, 0, stream>>>(zxbcdt, dtbuf, A_log, D_skip, hstart_s, ybuf_bf);
  // 5) out_proj split-K x4 -> part1; fused reduce(+hidden)+rmsnorm2 -> h2, hn_bf
  cvt_kernel<<<(DMODEL * DINNER / 8 + 255) / 256, 256, 0, stream>>>(out_proj_w, wbuf, DMODEL * DINNER / 8);
  gemm_ring<0, true><<<dim3(DMODEL / 128, L_SEQ / 128, 4), 256, 0, stream>>>(
      ybuf_bf, DINNER, wbuf, DINNER, part1, DMODEL, DINNER / 4, nullptr,
      nullptr, 0, 0);
  reduce_rms_kernel<<<L_SEQ, 256, 0, stream>>>(
      part1, L_SEQ * DMODEL, hidden, rms2_w, h2, hn_bf);
  // 6) gate+up merged: one GEMM over N = 2*INTER, bf16-only output
  cvt_kernel<<<(INTER * DMODEL / 8 + 255) / 256, 256, 0, stream>>>(gate_w, guw_bf, INTER * DMODEL / 8);
  cvt_kernel<<<(INTER * DMODEL / 8 + 255) / 256, 256, 0, stream>>>(up_w, guw_bf + (size_t)INTER * DMODEL, INTER * DMODEL / 8);
  gemm_ring<0, false><<<dim3(2 * INTER / 128, L_SEQ / 128, 1), 256, 0, stream>>>(
      hn_bf, DMODEL, guw_bf, DMODEL, nullptr, 0, DMODEL, nullptr,
      gu_bf, 0, 2 * INTER);
  // 7) hm = silu(gate) * up -> bf16
  silu_mul2_kernel<<<(L_SEQ * INTER / 8) / 256, 256, 0, stream>>>(
      gu_bf, hm_bf, L_SEQ * INTER / 8);
  // 8) down split-K x4 -> part2; reduce (+h2) -> out
  cvt_kernel<<<(DMODEL * INTER / 8 + 255) / 256, 256, 0, stream>>>(down_w, wbuf, DMODEL * INTER / 8);
  gemm_ring<0, true><<<dim3(DMODEL / 128, L_SEQ / 128, 4), 256, 0, stream>>>(
      hm_bf, INTER, wbuf, INTER, part2, DMODEL, INTER / 4, nullptr,
      nullptr, 0, 0);
  reduce_add_kernel<4><<<(L_SEQ * DMODEL / 4) / 256, 256, 0, stream>>>(
      part2, L_SEQ * DMODEL / 4, h2, out, L_SEQ * DMODEL / 4);
}

// Round 2
// 690.218 us; speedup vs baseline: 1.0254x; 1.0254x over previous
//
#include <hip/hip_runtime.h>
#include <cstdint>
#include <cstddef>

#define L_SEQ   1024
#define DMODEL  2048
#define DINNER  4096
#define DXB     1024
#define DSTATE  16
#define DTRANK  128
#define INTER   8192
#define ZROW    10368   // 2*DINNER + 2*DXB + DTRANK
#define ZROWP   10496   // padded to 41*256 for 256-wide GEMM tiles
#define NCHUNK  64
#define CLEN    16      // L_SEQ / NCHUNK

typedef __attribute__((ext_vector_type(8))) short  short8;
typedef __attribute__((ext_vector_type(4))) float  floatx4;
typedef unsigned short ushort_t;

__device__ __forceinline__ unsigned short f2bf(float f) {
  unsigned u = __float_as_uint(f);
  u += 0x7FFFu + ((u >> 16) & 1u);     // RNE
  return (unsigned short)(u >> 16);
}
__device__ __forceinline__ float bf2f(unsigned short h) {
  return __uint_as_float(((unsigned)h) << 16);
}

__device__ __forceinline__ void gl_lds16(const void* g, void* l) {
  __builtin_amdgcn_global_load_lds(
      (const __attribute__((address_space(1))) unsigned int*)g,
      (__attribute__((address_space(3))) unsigned int*)l,
      16, 0, 0);
}

// ---------------------------------------------------------------------------
// fp32 -> bf16 convert, 8 elems/thread
// ---------------------------------------------------------------------------
__global__ void __launch_bounds__(256) cvt_kernel(
    const float* __restrict__ src, ushort_t* __restrict__ dst, int n8)
{
  int idx = blockIdx.x * 256 + threadIdx.x;
  if (idx < n8) {
    const float4* s = (const float4*)src + (size_t)idx * 2;
    float4 v0 = s[0], v1 = s[1];
    union { ushort_t u[8]; uint4 v; } o;
    o.u[0] = f2bf(v0.x); o.u[1] = f2bf(v0.y); o.u[2] = f2bf(v0.z); o.u[3] = f2bf(v0.w);
    o.u[4] = f2bf(v1.x); o.u[5] = f2bf(v1.y); o.u[6] = f2bf(v1.z); o.u[7] = f2bf(v1.w);
    ((uint4*)dst)[idx] = o.v;
  }
}

// ---------------------------------------------------------------------------
// 256x256-tile GEMM, m201-style: BK=64, 512 threads = 8 waves (2M x 4N),
// per-wave 128x64 output (8x4 fragments of 16x16) -> 0.375 ds_reads/MFMA.
// LDS 128 KB: double-buffered [256][64] bf16 tiles for A and B.
//  - T2 XOR swizzle: 16B-chunk index ^= (row&7); staged via pre-swizzled
//    GLOBAL source (LDS dest linear, rule 21), read with matching XOR.
//    16-way bank conflict -> 2-way (free).
//  - T14/T4: stage(t+1) issued BEFORE s_waitcnt vmcnt(8); loads in flight
//    across the whole K-tile compute. 2 barriers per K=64 tile.
//  - T5: setprio around the two 32-MFMA clusters.
// C[m,n] = sum_k A[m,k]*W[n,k]; split-K via blockIdx.z.
// Cb != null: bf16 write for col in [col_lo, col_hi).
// Requires K % 64 == 0; M multiple of 256 covered by grid; W rows must be
// readable up to gridDim.x*256 (caller pads).
// ---------------------------------------------------------------------------
template <bool WF32>
__global__ void __launch_bounds__(512, 2) gemm256(
    const ushort_t* __restrict__ A, int lda,
    const ushort_t* __restrict__ W, int ldw,
    float* __restrict__ C, int ldc, int K,
    ushort_t* __restrict__ Cb, int col_lo, int col_hi, int ldcb)
{
  __shared__ alignas(16) ushort_t As[2 * 16384];   // 64 KB
  __shared__ alignas(16) ushort_t Bs[2 * 16384];   // 64 KB

  // XCD-aware bijective block swizzle (m204), then m-fastest decode so the
  // (up to) gy blocks sharing one weight panel land on the same XCD chunk.
  const int gx = gridDim.x, gy = gridDim.y;
  const int nwg = gx * gy * (int)gridDim.z;
  const int id  = ((int)blockIdx.z * gy + (int)blockIdx.y) * gx + (int)blockIdx.x;
  const int q = nwg >> 3, r = nwg & 7, xc = id & 7, dd = id >> 3;
  const int wg = (xc < r ? xc * (q + 1) : r * (q + 1) + (xc - r) * q) + dd;
  const int by = wg % gy;
  const int bx = (wg / gy) % gx;
  const int kz = wg / (gy * gx);

  const ushort_t* Ap = A + (size_t)kz * K;
  const ushort_t* Wp = W + (size_t)kz * K;
  float* Cz = nullptr;
  if constexpr (WF32) Cz = C + (size_t)kz * gy * 256 * ldc;

  const int m0 = by * 256, n0 = bx * 256;
  const int tid  = threadIdx.x;
  const int lane = tid & 63, wave = tid >> 6;
  const int wm = wave >> 2, wn = wave & 3;
  const int lrow = lane & 15, quad = lane >> 4;
  const int l8 = lane >> 3, c8 = lane & 7;

  // ---- staging: wave w covers rows [w*32, w*32+32), 4 instrs of 8 rows.
  // LDS linear layout [row][8 chunks of 16B]; stored chunk c8 holds global
  // chunk c8 ^ (row&7)  (row&7 == l8 here), so the global source is
  // pre-swizzled per lane.
  const ushort_t* gA = Ap + (size_t)(m0 + wave * 32 + l8) * lda + ((c8 ^ l8) << 3);
  const ushort_t* gW = Wp + (size_t)(n0 + wave * 32 + l8) * ldw + ((c8 ^ l8) << 3);
  ushort_t* lA = As + wave * 2048;
  ushort_t* lB = Bs + wave * 2048;

  auto STAGE = [&](int kt, int b) {
    const ushort_t* ga = gA + kt * 64;
    const ushort_t* gw = gW + kt * 64;
    ushort_t* la = lA + b * 16384;
    ushort_t* lb = lB + b * 16384;
#pragma unroll
    for (int j = 0; j < 4; ++j) {
      gl_lds16(ga + (size_t)j * 8 * lda, la + j * 512);
      gl_lds16(gw + (size_t)j * 8 * ldw, lb + j * 512);
    }
  };

  // ---- ds_read addressing (elems): row_local*64 + swizzled_chunk*8
  const int rA0 = (wm * 128 + lrow) * 64;
  const int rB0 = (wn * 64  + lrow) * 64;
  const int ck0 = ((quad     ^ (lrow & 7)) << 3);   // k-chunk 0 (k 0..31 of tile)
  const int ck1 = (((4 | quad) ^ (lrow & 7)) << 3); // k-chunk 1 (k 32..63)

  floatx4 acc[8][4];
#pragma unroll
  for (int f = 0; f < 8; ++f)
#pragma unroll
    for (int n = 0; n < 4; ++n) acc[f][n] = (floatx4){0.f, 0.f, 0.f, 0.f};

  const int T = K >> 6;
  STAGE(0, 0);

  for (int tt = 0; tt < T; ++tt) {
    if (tt + 1 < T) {
      STAGE(tt + 1, (tt + 1) & 1);
      asm volatile("s_waitcnt vmcnt(8)" ::: "memory");   // retire tile tt's 8
    } else {
      asm volatile("s_waitcnt vmcnt(0)" ::: "memory");
    }
    __builtin_amdgcn_s_barrier();       // tile tt visible to all waves

    const int bo = (tt & 1) * 16384;
    short8 Bfr[4][2], Afr[4][2];
#pragma unroll
    for (int n = 0; n < 4; ++n) {
      Bfr[n][0] = *(const short8*)&Bs[bo + rB0 + n * 1024 + ck0];
      Bfr[n][1] = *(const short8*)&Bs[bo + rB0 + n * 1024 + ck1];
    }
#pragma unroll
    for (int f = 0; f < 4; ++f) {
      Afr[f][0] = *(const short8*)&As[bo + rA0 + f * 1024 + ck0];
      Afr[f][1] = *(const short8*)&As[bo + rA0 + f * 1024 + ck1];
    }
    __builtin_amdgcn_s_setprio(1);
#pragma unroll
    for (int f = 0; f < 4; ++f)
#pragma unroll
      for (int n = 0; n < 4; ++n) {
        acc[f][n] = __builtin_amdgcn_mfma_f32_16x16x32_bf16(Afr[f][0], Bfr[n][0], acc[f][n], 0, 0, 0);
        acc[f][n] = __builtin_amdgcn_mfma_f32_16x16x32_bf16(Afr[f][1], Bfr[n][1], acc[f][n], 0, 0, 0);
      }
    __builtin_amdgcn_s_setprio(0);
#pragma unroll
    for (int f = 0; f < 4; ++f) {
      Afr[f][0] = *(const short8*)&As[bo + rA0 + (f + 4) * 1024 + ck0];
      Afr[f][1] = *(const short8*)&As[bo + rA0 + (f + 4) * 1024 + ck1];
    }
    __builtin_amdgcn_s_setprio(1);
#pragma unroll
    for (int f = 0; f < 4; ++f)
#pragma unroll
      for (int n = 0; n < 4; ++n) {
        acc[f + 4][n] = __builtin_amdgcn_mfma_f32_16x16x32_bf16(Afr[f][0], Bfr[n][0], acc[f + 4][n], 0, 0, 0);
        acc[f + 4][n] = __builtin_amdgcn_mfma_f32_16x16x32_bf16(Afr[f][1], Bfr[n][1], acc[f + 4][n], 0, 0, 0);
      }
    __builtin_amdgcn_s_setprio(0);
    __builtin_amdgcn_s_barrier();       // all reads of buf done -> reusable
  }

#pragma unroll
  for (int f = 0; f < 8; ++f)
#pragma unroll
    for (int n = 0; n < 4; ++n)
#pragma unroll
      for (int r = 0; r < 4; ++r) {
        int row = m0 + wm * 128 + f * 16 + quad * 4 + r;
        int col = n0 + wn * 64 + n * 16 + lrow;
        float v = acc[f][n][r];
        if constexpr (WF32)
          Cz[(size_t)row * ldc + col] = v;
        if (Cb != nullptr && col >= col_lo && col < col_hi)
          Cb[(size_t)row * ldcb + (col - col_lo)] = f2bf(v);
      }
}

// ---------------------------------------------------------------------------
// GEMM ring-4 (128x128), kept for the small dt GEMM (K=128).
// EPI: 1 => softplus(acc + aux[col]).
// ---------------------------------------------------------------------------
template <int EPI, bool WF32>
__global__ void __launch_bounds__(256, 2) gemm_ring(
    const ushort_t* __restrict__ A, int lda,
    const ushort_t* __restrict__ W, int ldw,
    float* __restrict__ C, int ldc, int K,
    const float* __restrict__ aux,
    ushort_t* __restrict__ Cb, int col_lo, int ldcb)
{
  constexpr int ASZ = 128 * 32;
  __shared__ alignas(16) ushort_t As[4 * ASZ];
  __shared__ alignas(16) ushort_t Bs[4 * ASZ];

  const int gx = gridDim.x, gy = gridDim.y;
  const int nwg = gx * gy * (int)gridDim.z;
  const int id  = ((int)blockIdx.z * gy + (int)blockIdx.y) * gx + (int)blockIdx.x;
  const int q = nwg >> 3, r = nwg & 7, xc = id & 7, dd = id >> 3;
  const int wg = (xc < r ? xc * (q + 1) : r * (q + 1) + (xc - r) * q) + dd;
  const int bx  = wg % gx;
  const int byz = wg / gx;
  const int by  = byz % gy;
  const int kz  = byz / gy;

  A += (size_t)kz * K;
  W += (size_t)kz * K;
  float* Cz = nullptr;
  if constexpr (WF32) Cz = C + (size_t)kz * gy * 128 * ldc;

  const int m0 = by * 128, n0 = bx * 128;
  const int t = threadIdx.x;
  const int lane = t & 63, wave = t >> 6;
  const int wm = wave & 1, wn = wave >> 1;
  const int lrow = lane & 15, quad = lane >> 4;
  const int chunk = (quad ^ (lrow & 3)) << 3;

  const int srow = wave * 16 + (lane >> 2);
  const int skof = (((lane & 3) ^ ((lane >> 2) & 3)) << 3);

  const ushort_t* gA0 = A + (size_t)(m0 +  0 + srow) * lda + skof;
  const ushort_t* gA1 = A + (size_t)(m0 + 64 + srow) * lda + skof;
  const ushort_t* gW0 = W + (size_t)(n0 +  0 + srow) * ldw + skof;
  const ushort_t* gW1 = W + (size_t)(n0 + 64 + srow) * ldw + skof;
  ushort_t* lA0 = As + wave * 512;
  ushort_t* lA1 = As + 2048 + wave * 512;
  ushort_t* lB0 = Bs + wave * 512;
  ushort_t* lB1 = Bs + 2048 + wave * 512;

  floatx4 zero = {0.f, 0.f, 0.f, 0.f};
  floatx4 acc[4][4];
#pragma unroll
  for (int a = 0; a < 4; ++a)
#pragma unroll
    for (int b = 0; b < 4; ++b) acc[a][b] = zero;

  const int T = K >> 5;
#pragma unroll
  for (int p = 0; p < 3; ++p) {
    const int ko = p * 32, s = p * ASZ;
    gl_lds16(gA0 + ko, lA0 + s);
    gl_lds16(gA1 + ko, lA1 + s);
    gl_lds16(gW0 + ko, lB0 + s);
    gl_lds16(gW1 + ko, lB1 + s);
  }

  for (int tt = 0; tt < T; ++tt) {
    if (tt + 2 < T)      asm volatile("s_waitcnt vmcnt(8)" ::: "memory");
    else if (tt + 1 < T) asm volatile("s_waitcnt vmcnt(4)" ::: "memory");
    else                 asm volatile("s_waitcnt vmcnt(0)" ::: "memory");
    __builtin_amdgcn_s_barrier();
    __builtin_amdgcn_sched_barrier(0);

    if (tt + 3 < T) {
      const int ko = (tt + 3) * 32;
      const int s  = ((tt + 3) & 3) * ASZ;
      gl_lds16(gA0 + ko, lA0 + s);
      gl_lds16(gA1 + ko, lA1 + s);
      gl_lds16(gW0 + ko, lB0 + s);
      gl_lds16(gW1 + ko, lB1 + s);
    }

    const int cs = (tt & 3) * ASZ;
    short8 af[4], bf_[4];
#pragma unroll
    for (int mi = 0; mi < 4; ++mi)
      af[mi] = *(const short8*)&As[cs + (wm * 64 + mi * 16 + lrow) * 32 + chunk];
#pragma unroll
    for (int ni = 0; ni < 4; ++ni)
      bf_[ni] = *(const short8*)&Bs[cs + (wn * 64 + ni * 16 + lrow) * 32 + chunk];
#pragma unroll
    for (int mi = 0; mi < 4; ++mi)
#pragma unroll
      for (int ni = 0; ni < 4; ++ni)
        acc[mi][ni] = __builtin_amdgcn_mfma_f32_16x16x32_bf16(af[mi], bf_[ni], acc[mi][ni], 0, 0, 0);
  }

#pragma unroll
  for (int mi = 0; mi < 4; ++mi)
#pragma unroll
    for (int ni = 0; ni < 4; ++ni)
#pragma unroll
      for (int reg = 0; reg < 4; ++reg) {
        int row = m0 + wm * 64 + mi * 16 + quad * 4 + reg;
        int col = n0 + wn * 64 + ni * 16 + lrow;
        float v = acc[mi][ni][reg];
        if (EPI == 1) {
          v += aux[col];
          v = (v > 20.f) ? v : log1pf(__expf(v));
        }
        if constexpr (WF32)
          Cz[(size_t)row * ldc + col] = v;
        if (Cb != nullptr && col >= col_lo)
          Cb[(size_t)row * ldcb + (col - col_lo)] = f2bf(v);
      }
}

// ---------------------------------------------------------------------------
// split-K reduce: out = aux + sum_{s<S} part[s]   (fp32, float4)
// ---------------------------------------------------------------------------
template <int S>
__global__ void __launch_bounds__(256) reduce_add_kernel(
    const float* __restrict__ part, int stride4,
    const float* __restrict__ aux, float* __restrict__ out, int n4)
{
  int idx = blockIdx.x * 256 + threadIdx.x;
  if (idx < n4) {
    float4 v = ((const float4*)aux)[idx];
#pragma unroll
    for (int s = 0; s < S; ++s) {
      float4 p = ((const float4*)part)[(size_t)s * stride4 + idx];
      v.x += p.x; v.y += p.y; v.z += p.z; v.w += p.w;
    }
    ((float4*)out)[idx] = v;
  }
}

// ---------------------------------------------------------------------------
// Fused: h2 = hidden + sum_s part[s]; hn_bf = rmsnorm(h2)*w  (one block/row)
// ---------------------------------------------------------------------------
template <int S>
__global__ void __launch_bounds__(256) reduce_rms_kernel(
    const float* __restrict__ part, int stride,   // stride in floats
    const float* __restrict__ hidden,
    const float* __restrict__ w,
    float* __restrict__ h2, ushort_t* __restrict__ hn)
{
  const int row = blockIdx.x;
  const int c0 = threadIdx.x * 8;            // 2048/256 = 8 floats/thread
  float4 v0 = *(const float4*)(hidden + (size_t)row * DMODEL + c0);
  float4 v1 = *(const float4*)(hidden + (size_t)row * DMODEL + c0 + 4);
#pragma unroll
  for (int s = 0; s < S; ++s) {
    const float* p = part + (size_t)s * stride + (size_t)row * DMODEL + c0;
    float4 p0 = *(const float4*)p;
    float4 p1 = *(const float4*)(p + 4);
    v0.x += p0.x; v0.y += p0.y; v0.z += p0.z; v0.w += p0.w;
    v1.x += p1.x; v1.y += p1.y; v1.z += p1.z; v1.w += p1.w;
  }
  *(float4*)(h2 + (size_t)row * DMODEL + c0)     = v0;
  *(float4*)(h2 + (size_t)row * DMODEL + c0 + 4) = v1;
  float ss = v0.x*v0.x + v0.y*v0.y + v0.z*v0.z + v0.w*v0.w
           + v1.x*v1.x + v1.y*v1.y + v1.z*v1.z + v1.w*v1.w;
#pragma unroll
  for (int off = 32; off > 0; off >>= 1) ss += __shfl_down(ss, off);
  __shared__ float red[5];
  const int lane = threadIdx.x & 63, wv = threadIdx.x >> 6;
  if (lane == 0) red[wv] = ss;
  __syncthreads();
  if (threadIdx.x == 0)
    red[4] = rsqrtf((red[0] + red[1] + red[2] + red[3]) / (float)DMODEL + 1e-5f);
  __syncthreads();
  const float scale = red[4];
  float4 w0 = *(const float4*)(w + c0);
  float4 w1 = *(const float4*)(w + c0 + 4);
  union { ushort_t u[8]; uint4 q; } o;
  o.u[0] = f2bf(v0.x * scale * w0.x); o.u[1] = f2bf(v0.y * scale * w0.y);
  o.u[2] = f2bf(v0.z * scale * w0.z); o.u[3] = f2bf(v0.w * scale * w0.w);
  o.u[4] = f2bf(v1.x * scale * w1.x); o.u[5] = f2bf(v1.y * scale * w1.y);
  o.u[6] = f2bf(v1.z * scale * w1.z); o.u[7] = f2bf(v1.w * scale * w1.w);
  *(uint4*)(hn + (size_t)row * DMODEL + c0) = o.q;
}

// ---------------------------------------------------------------------------
// RMSNorm (fp32 in, bf16 out)
// ---------------------------------------------------------------------------
__global__ void __launch_bounds__(256) rmsnorm_kernel(
    const float* __restrict__ x, const float* __restrict__ w,
    ushort_t* __restrict__ out)
{
  const int row = blockIdx.x;
  const float* xr = x + (size_t)row * DMODEL;
  float ss = 0.f;
#pragma unroll
  for (int c = threadIdx.x * 4; c < DMODEL; c += 256 * 4) {
    float4 v = *(const float4*)(xr + c);
    ss += v.x * v.x + v.y * v.y + v.z * v.z + v.w * v.w;
  }
#pragma unroll
  for (int off = 32; off > 0; off >>= 1) ss += __shfl_down(ss, off);
  __shared__ float red[5];
  const int lane = threadIdx.x & 63, wv = threadIdx.x >> 6;
  if (lane == 0) red[wv] = ss;
  __syncthreads();
  if (threadIdx.x == 0)
    red[4] = rsqrtf((red[0] + red[1] + red[2] + red[3]) / (float)DMODEL + 1e-5f);
  __syncthreads();
  const float scale = red[4];
  ushort_t* orow = out + (size_t)row * DMODEL;
#pragma unroll
  for (int c = threadIdx.x * 4; c < DMODEL; c += 256 * 4) {
    float4 v  = *(const float4*)(xr + c);
    float4 w4 = *(const float4*)(w + c);
    ushort4 o;
    o.x = f2bf(v.x * scale * w4.x); o.y = f2bf(v.y * scale * w4.y);
    o.z = f2bf(v.z * scale * w4.z); o.w = f2bf(v.w * scale * w4.w);
    *(ushort4*)(orow + c) = o;
  }
}

// ---------------------------------------------------------------------------
// Chunk-parallel selective scan (zx row stride = ZROWP).
// ---------------------------------------------------------------------------
__global__ void __launch_bounds__(256) scan_phase1(
    const float* __restrict__ zx, const float* __restrict__ dt,
    const float* __restrict__ A_log,
    float* __restrict__ hend, float* __restrict__ sdtb)
{
  const int gt = blockIdx.x * 256 + threadIdx.x;   // 0..262143
  const int i  = gt & 4095;
  const int c  = gt >> 12;
  const int l0 = c * CLEN;

  float a[16];
  *(float4*)&a[0]  = *(const float4*)(A_log + i * 16 + 0);
  *(float4*)&a[4]  = *(const float4*)(A_log + i * 16 + 4);
  *(float4*)&a[8]  = *(const float4*)(A_log + i * 16 + 8);
  *(float4*)&a[12] = *(const float4*)(A_log + i * 16 + 12);
#pragma unroll
  for (int n = 0; n < 16; ++n) a[n] = -__expf(a[n]);

  float h[16];
#pragma unroll
  for (int n = 0; n < 16; ++n) h[n] = 0.f;
  float sdt = 0.f;

  const int xci = DINNER + ((i >> 6) << 4) + (i & 15);
  const int bci = DINNER + DXB + ((i >> 6) << 4);
  const float* zr = zx + (size_t)l0 * ZROWP;
  const float* dr = dt + (size_t)l0 * DINNER + i;

#pragma unroll 4
  for (int l = 0; l < CLEN; ++l) {
    const float* row = zr + (size_t)l * ZROWP;
    const float d = dr[l * DINNER];
    const float x = row[xci];
    float B[16];
    *(float4*)&B[0]  = *(const float4*)(row + bci);
    *(float4*)&B[4]  = *(const float4*)(row + bci + 4);
    *(float4*)&B[8]  = *(const float4*)(row + bci + 8);
    *(float4*)&B[12] = *(const float4*)(row + bci + 12);
    sdt += d;
    const float dtx = d * x;
#pragma unroll
    for (int n = 0; n < 16; ++n)
      h[n] = __expf(d * a[n]) * h[n] + dtx * B[n];
  }

  float* he = hend + ((size_t)c * 65536 + i * 16);
  *(float4*)(he + 0)  = *(float4*)&h[0];
  *(float4*)(he + 4)  = *(float4*)&h[4];
  *(float4*)(he + 8)  = *(float4*)&h[8];
  *(float4*)(he + 12) = *(float4*)&h[12];
  sdtb[c * 4096 + i] = sdt;
}

__global__ void __launch_bounds__(256) scan_phase2(
    const float* __restrict__ hend, const float* __restrict__ sdtb,
    const float* __restrict__ A_log,
    float* __restrict__ hstart)
{
  const int cs = blockIdx.x * 256 + threadIdx.x;   // 0..65535 = i*16+n
  const float a = -__expf(A_log[cs]);
  const int i  = cs >> 4;
  float H = 0.f;
#pragma unroll 8
  for (int c = 0; c < NCHUNK; ++c) {
    hstart[c * 65536 + cs] = H;
    H = __expf(a * sdtb[c * 4096 + i]) * H + hend[c * 65536 + cs];
  }
}

__global__ void __launch_bounds__(256) scan_phase3(
    const float* __restrict__ zx, const float* __restrict__ dt,
    const float* __restrict__ A_log, const float* __restrict__ D_skip,
    const float* __restrict__ hstart,
    ushort_t* __restrict__ y)
{
  const int gt = blockIdx.x * 256 + threadIdx.x;   // 0..262143
  const int i  = gt & 4095;
  const int c  = gt >> 12;
  const int l0 = c * CLEN;

  float a[16];
  *(float4*)&a[0]  = *(const float4*)(A_log + i * 16 + 0);
  *(float4*)&a[4]  = *(const float4*)(A_log + i * 16 + 4);
  *(float4*)&a[8]  = *(const float4*)(A_log + i * 16 + 8);
  *(float4*)&a[12] = *(const float4*)(A_log + i * 16 + 12);
#pragma unroll
  for (int n = 0; n < 16; ++n) a[n] = -__expf(a[n]);
  const float dsk = D_skip[i];

  float h[16];
  const float* hs = hstart + ((size_t)c * 65536 + i * 16);
  *(float4*)&h[0]  = *(const float4*)(hs + 0);
  *(float4*)&h[4]  = *(const float4*)(hs + 4);
  *(float4*)&h[8]  = *(const float4*)(hs + 8);
  *(float4*)&h[12] = *(const float4*)(hs + 12);

  const int xci = DINNER + ((i >> 6) << 4) + (i & 15);
  const int bci = DINNER + DXB + ((i >> 6) << 4);
  const int cci = DINNER + 2 * DXB + (i & ~15);
  const float* zr = zx + (size_t)l0 * ZROWP;
  const float* dr = dt + (size_t)l0 * DINNER + i;
  ushort_t*    py = y + (size_t)l0 * DINNER + i;

#pragma unroll 2
  for (int l = 0; l < CLEN; ++l) {
    const float* row = zr + (size_t)l * ZROWP;
    const float d = dr[l * DINNER];
    const float x = row[xci];
    const float z = row[i];
    float B[16], C[16];
    *(float4*)&B[0]  = *(const float4*)(row + bci);
    *(float4*)&B[4]  = *(const float4*)(row + bci + 4);
    *(float4*)&B[8]  = *(const float4*)(row + bci + 8);
    *(float4*)&B[12] = *(const float4*)(row + bci + 12);
    *(float4*)&C[0]  = *(const float4*)(row + cci);
    *(float4*)&C[4]  = *(const float4*)(row + cci + 4);
    *(float4*)&C[8]  = *(const float4*)(row + cci + 8);
    *(float4*)&C[12] = *(const float4*)(row + cci + 12);
    const float dtx = d * x;
    float p0 = 0.f, p1 = 0.f, p2 = 0.f, p3 = 0.f;
#pragma unroll
    for (int n = 0; n < 4; ++n) {
      h[n]      = __expf(d * a[n])      * h[n]      + dtx * B[n];
      h[n + 4]  = __expf(d * a[n + 4])  * h[n + 4]  + dtx * B[n + 4];
      h[n + 8]  = __expf(d * a[n + 8])  * h[n + 8]  + dtx * B[n + 8];
      h[n + 12] = __expf(d * a[n + 12]) * h[n + 12] + dtx * B[n + 12];
      p0 += C[n] * h[n];
      p1 += C[n + 4] * h[n + 4];
      p2 += C[n + 8] * h[n + 8];
      p3 += C[n + 12] * h[n + 12];
    }
    const float p = (p0 + p1) + (p2 + p3);
    const float sz = z / (1.f + __expf(-z));
    py[l * DINNER] = f2bf((p + dsk * x) * sz);
  }
}

// ---------------------------------------------------------------------------
// hm = silu(gate) * up, gate/up packed in one [L][2*INTER] bf16 buffer
// ---------------------------------------------------------------------------
__global__ void __launch_bounds__(256) silu_mul2_kernel(
    const ushort_t* __restrict__ gu, ushort_t* __restrict__ out, int n8)
{
  const int idx = blockIdx.x * 256 + threadIdx.x;
  if (idx < n8) {
    const int row = idx >> 10;            // INTER/8 = 1024 chunks per row
    const int j   = (idx & 1023) << 3;
    const ushort_t* gp = gu + (size_t)row * (2 * INTER) + j;
    union { uint4 v; ushort_t u[8]; } gv, uv, ov;
    gv.v = *(const uint4*)gp;
    uv.v = *(const uint4*)(gp + INTER);
#pragma unroll
    for (int jj = 0; jj < 8; ++jj) {
      float gf = bf2f(gv.u[jj]), uf = bf2f(uv.u[jj]);
      ov.u[jj] = f2bf(gf / (1.f + __expf(-gf)) * uf);
    }
    *(uint4*)(out + (size_t)row * INTER + j) = ov.v;
  }
}

// ---------------------------------------------------------------------------
extern "C" void kernel_launch(void* const* d_in, const int* in_sizes, int n_in,
                              void* d_out, int out_size, void* d_ws, size_t ws_size,
                              hipStream_t stream)
{
  const float* hidden    = (const float*)d_in[0];
  const float* rms1_w    = (const float*)d_in[1];
  const float* in_proj_w = (const float*)d_in[2];
  const float* dt_proj_w = (const float*)d_in[3];
  const float* dt_proj_b = (const float*)d_in[4];
  const float* A_log     = (const float*)d_in[5];
  const float* D_skip    = (const float*)d_in[6];
  const float* out_proj_w= (const float*)d_in[7];
  const float* rms2_w    = (const float*)d_in[8];
  const float* gate_w    = (const float*)d_in[9];
  const float* up_w      = (const float*)d_in[10];
  const float* down_w    = (const float*)d_in[11];
  float* out = (float*)d_out;

  char* ws = (char*)d_ws;
  // ---- arena (max end 177,471,488 == proven ws floor) ----
  ushort_t* h_norm_bf = (ushort_t*)(ws + 0);            // 4 MB  [step1->2]
  float*    h2        = (float*)   (ws + 4194304);      // 8 MB  [reduce_rms->end]
  ushort_t* hn_bf     = (ushort_t*)(ws + 12582912);     // 4 MB  [reduce_rms->gate+up]
  // region D [16,777,216 ..): zxbcdt(43.0MB) -> part1(64MB) -> guw(64MB) -> part2(64MB)
  float*    zxbcdt    = (float*)   (ws + 16777216);     // 1024*10496*4 = 42,991,616
  float*    part1     = (float*)   (ws + 16777216);     // 64 MB (after scan)
  ushort_t* guw_bf    = (ushort_t*)(ws + 16777216);     // 64 MB (after reduce_rms)
  float*    part2     = (float*)   (ws + 16777216);     // 64 MB (after gate+up gemm)
  ushort_t* gu_bf     = (ushort_t*)(ws + 83886080);     // 32 MB [gemm->silu] (over dtbuf/hend, dead)
  ushort_t* hm_bf     = (ushort_t*)(ws + 117440512);    // 16 MB [silu->down] (over hstart, dead)
  float*    dtbuf     = (float*)   (ws + 83886080);     // 16 MB [dt gemm->scan3]
  float*    hend_s    = (float*)   (ws + 100663296);    // 16 MB [scan]
  float*    hstart_s  = (float*)   (ws + 117440512);    // 16 MB [scan]
  ushort_t* wbuf      = (ushort_t*)(ws + 134217728);    // 42,467,328 (+512KB read overrun ok)
  ushort_t* ybuf_bf   = (ushort_t*)(ws + 167772160);    // 8 MB  [scan3->out_proj]
  float*    sdtb_s    = (float*)   (ws + 176160768);    // 1 MB  [scan]
  ushort_t* dtA_bf    = (ushort_t*)(ws + 177209344);    // 256 KB -> ends 177,471,488

  // 1) rmsnorm1 -> bf16
  rmsnorm_kernel<<<L_SEQ, 256, 0, stream>>>(hidden, rms1_w, h_norm_bf);
  // 2) in_proj -> zxbcdt fp32 (row stride ZROWP; cols >= ZROW are pad garbage,
  //    never read) + bf16 dt slice (col_hi-guarded)
  cvt_kernel<<<(ZROW * DMODEL / 8 + 255) / 256, 256, 0, stream>>>(in_proj_w, wbuf, ZROW * DMODEL / 8);
  gemm256<true><<<dim3(ZROWP / 256, L_SEQ / 256, 1), 512, 0, stream>>>(
      h_norm_bf, DMODEL, wbuf, DMODEL, zxbcdt, ZROWP, DMODEL,
      dtA_bf, 2 * DINNER + 2 * DXB, ZROW, DTRANK);
  // 3) dt = softplus(dt_in @ dt_proj_w.T + b)   (small K=128: ring kernel)
  cvt_kernel<<<(DINNER * DTRANK / 8 + 255) / 256, 256, 0, stream>>>(dt_proj_w, wbuf, DINNER * DTRANK / 8);
  gemm_ring<1, true><<<dim3(DINNER / 128, L_SEQ / 128, 1), 256, 0, stream>>>(
      dtA_bf, DTRANK, wbuf, DTRANK, dtbuf, DINNER, DTRANK, dt_proj_b,
      nullptr, 0, 0);
  // 4) chunk-parallel scan -> ybuf bf16
  scan_phase1<<<1024, 256, 0, stream>>>(zxbcdt, dtbuf, A_log, hend_s, sdtb_s);
  scan_phase2<<<256, 256, 0, stream>>>(hend_s, sdtb_s, A_log, hstart_s);
  scan_phase3<<<1024, 256, 0, stream>>>(zxbcdt, dtbuf, A_log, D_skip, hstart_s, ybuf_bf);
  // 5) out_proj split-K x8 -> part1; fused reduce(+hidden)+rmsnorm2
  cvt_kernel<<<(DMODEL * DINNER / 8 + 255) / 256, 256, 0, stream>>>(out_proj_w, wbuf, DMODEL * DINNER / 8);
  gemm256<true><<<dim3(DMODEL / 256, L_SEQ / 256, 8), 512, 0, stream>>>(
      ybuf_bf, DINNER, wbuf, DINNER, part1, DMODEL, DINNER / 8,
      nullptr, 0, 0, 0);
  reduce_rms_kernel<8><<<L_SEQ, 256, 0, stream>>>(
      part1, L_SEQ * DMODEL, hidden, rms2_w, h2, hn_bf);
  // 6) gate+up merged: one GEMM over N = 2*INTER (256 blocks), bf16 out
  cvt_kernel<<<(INTER * DMODEL / 8 + 255) / 256, 256, 0, stream>>>(gate_w, guw_bf, INTER * DMODEL / 8);
  cvt_kernel<<<(INTER * DMODEL / 8 + 255) / 256, 256, 0, stream>>>(up_w, guw_bf + (size_t)INTER * DMODEL, INTER * DMODEL / 8);
  gemm256<false><<<dim3(2 * INTER / 256, L_SEQ / 256, 1), 512, 0, stream>>>(
      hn_bf, DMODEL, guw_bf, DMODEL, nullptr, 0, DMODEL,
      gu_bf, 0, 2 * INTER, 2 * INTER);
  // 7) hm = silu(gate) * up -> bf16
  silu_mul2_kernel<<<(L_SEQ * INTER / 8) / 256, 256, 0, stream>>>(
      gu_bf, hm_bf, L_SEQ * INTER / 8);
  // 8) down split-K x8 -> part2; reduce (+h2) -> out
  cvt_kernel<<<(DMODEL * INTER / 8 + 255) / 256, 256, 0, stream>>>(down_w, wbuf, DMODEL * INTER / 8);
  gemm256<true><<<dim3(DMODEL / 256, L_SEQ / 256, 8), 512, 0, stream>>>(
      hm_bf, INTER, wbuf, INTER, part2, DMODEL, INTER / 8,
      nullptr, 0, 0, 0);
  reduce_add_kernel<8><<<(L_SEQ * DMODEL / 4) / 256, 256, 0, stream>>>(
      part2, L_SEQ * DMODEL / 4, h2, out, L_SEQ * DMODEL / 4);
}